// Round 10
// baseline (290.282 us; speedup 1.0000x reference)
//
#include <hip/hip_runtime.h>
#include <math.h>

// Problem constants: B=2, T=2048, D=768, H=12, HS=64, FF=3072, HALF=1536
#define TDIM 2048
#define DDIM 768
#define NH   12
#define NROWS 4096            // B*T
#define EPSV 1e-8f
#define SCALE 0.03608439182435161f   // 768^-0.5  (ref scales by D, not HS)

typedef __bf16 bf16_t;
typedef bf16_t bf16x8 __attribute__((ext_vector_type(8)));
typedef bf16_t bf16x4 __attribute__((ext_vector_type(4)));
typedef float  floatx4 __attribute__((ext_vector_type(4)));

// async global->LDS, 16B per lane; LDS dest = wave-uniform base + lane*16
__device__ __forceinline__ void glds16(const bf16_t* g, bf16_t* l) {
    __builtin_amdgcn_global_load_lds(
        (const __attribute__((address_space(1))) void*)g,
        (__attribute__((address_space(3))) void*)l, 16, 0, 0);
}

// ------------- unified weight repack: 64x64 fp32->bf16 tile transpose --------
// 1440 blocks: [0,144) Wo, [144,720) W1, [720,1008) W2, [1008,1440) QKV pack.
__global__ __launch_bounds__(256) void pack_all(
    const float* __restrict__ Wq, const float* __restrict__ Wk,
    const float* __restrict__ Wv, const float* __restrict__ Wo,
    const float* __restrict__ W1, const float* __restrict__ W2,
    bf16_t* __restrict__ qkvw, bf16_t* __restrict__ wo,
    bf16_t* __restrict__ w1, bf16_t* __restrict__ w2)
{
    int bid = blockIdx.x;
    const float* src; bf16_t* dst;
    int srcld, dstld, k0, n0;
    if (bid < 144) {                       // Wo: K=768, N=768 (12x12)
        int kx = bid % 12, nx = bid / 12;
        src = Wo; dst = wo; srcld = 768; dstld = 768; k0 = kx * 64; n0 = nx * 64;
    } else if (bid < 720) {                // W1: K=768, N=3072 (12x48)
        int t = bid - 144; int kx = t % 12, nx = t / 12;
        src = W1; dst = w1; srcld = 3072; dstld = 768; k0 = kx * 64; n0 = nx * 64;
    } else if (bid < 1008) {               // W2: K=1536, N=768 (24x12)
        int t = bid - 720; int kx = t % 24, nx = t / 24;
        src = W2; dst = w2; srcld = 768; dstld = 1536; k0 = kx * 64; n0 = nx * 64;
    } else {                               // QKV: 36 mats (768x64), 12 k-tiles
        int t = bid - 1008; int kx = t % 12, y = t / 12;
        int sel = y / 12, h = y - sel * 12;
        src = ((sel == 0) ? Wq : (sel == 1) ? Wk : Wv) + (size_t)h * 768 * 64;
        dst = qkvw + (size_t)(sel * 768 + h * 64) * 768;
        srcld = 64; dstld = 768; k0 = kx * 64; n0 = 0;
    }
    __shared__ float Ts[64][65];
    int tid = threadIdx.x;
    int r = tid >> 2, c = (tid & 3) * 16;
    const float* s = src + (size_t)(k0 + r) * srcld + n0 + c;
    #pragma unroll
    for (int i = 0; i < 4; i++) {
        float4 t = *(const float4*)(s + i * 4);
        Ts[r][c + i*4 + 0] = t.x; Ts[r][c + i*4 + 1] = t.y;
        Ts[r][c + i*4 + 2] = t.z; Ts[r][c + i*4 + 3] = t.w;
    }
    __syncthreads();
    int n = tid >> 2, kk = (tid & 3) * 16;
    bf16x8 o0, o1;
    #pragma unroll
    for (int i = 0; i < 8; i++) {
        o0[i] = (bf16_t)Ts[kk + i][n];
        o1[i] = (bf16_t)Ts[kk + 8 + i][n];
    }
    bf16_t* d = dst + (size_t)(n0 + n) * dstld + k0 + kk;
    *(bf16x8*)d = o0;
    *(bf16x8*)(d + 8) = o1;
}

// ---------------- RMSNorm -> bf16 ----------------
__global__ __launch_bounds__(256) void rmsnorm_bf(
    const float* __restrict__ x, const float* __restrict__ g,
    bf16_t* __restrict__ out)
{
    int row = blockIdx.x;
    int tid = threadIdx.x;
    const float* xr = x + (size_t)row * DDIM;
    float v0 = xr[tid], v1 = xr[tid + 256], v2 = xr[tid + 512];
    float s = v0*v0 + v1*v1 + v2*v2;
    #pragma unroll
    for (int off = 32; off > 0; off >>= 1)
        s += __shfl_down(s, off, 64);
    __shared__ float red[4];
    __shared__ float tot;
    if ((tid & 63) == 0) red[tid >> 6] = s;
    __syncthreads();
    if (tid == 0) tot = red[0] + red[1] + red[2] + red[3];
    __syncthreads();
    float rms = sqrtf(tot * (1.0f / DDIM));
    float inv = 1.0f / (rms + EPSV);
    bf16_t* orow = out + (size_t)row * DDIM;
    orow[tid]       = (bf16_t)(g[tid]       * v0 * inv);
    orow[tid + 256] = (bf16_t)(g[tid + 256] * v1 * inv);
    orow[tid + 512] = (bf16_t)(g[tid + 512] * v2 * inv);
}

// ---------------- bf16 MFMA GEMM, BK=64 twin-buffer (R6 structure), C^T out --
template<int TM>
__global__ __launch_bounds__(256) void gemm_bf16(
    const bf16_t* __restrict__ A, const bf16_t* __restrict__ BT, int K,
    float* __restrict__ Cf, bf16_t* __restrict__ Cb, int ldc,
    const float* __restrict__ bias, const float* __restrict__ resid)
{
    constexpr int MT = TM / 32;           // m-frags per wave (4 or 2)
    __shared__ bf16_t As0[TM][32], As1[TM][32];      // 64B rows (m97 layout)
    __shared__ bf16_t Bs0[128][32], Bs1[128][32];
    int tid = threadIdx.x;
    int wave = tid >> 6, lane = tid & 63;
    int lrow = lane & 15, quad = lane >> 4;
    int wm = wave >> 1, wn = wave & 1;

    int m0 = blockIdx.y * TM;
    int n0 = blockIdx.x * 128;

    int srow = lane >> 2, scol = (lane & 3) * 8;     // 16 rows x 8 elems / glds
    const bf16_t* Ag = A  + ((size_t)m0 + wave * (TM/4) + srow) * K + scol;
    const bf16_t* Bg = BT + ((size_t)n0 + wave * 32 + srow) * K + scol;

    floatx4 acc[MT][4];
    #pragma unroll
    for (int mt = 0; mt < MT; mt++)
        #pragma unroll
        for (int nt = 0; nt < 4; nt++)
            #pragma unroll
            for (int r = 0; r < 4; r++) acc[mt][nt][r] = 0.f;

    for (int k0 = 0; k0 < K; k0 += 64) {
        __syncthreads();
        #pragma unroll
        for (int i = 0; i < TM/64; i++) {            // 2 (TM=128) or 1 (TM=64)
            glds16(Ag + (size_t)(i*16) * K + k0,      &As0[wave*(TM/4) + i*16][0]);
            glds16(Ag + (size_t)(i*16) * K + k0 + 32, &As1[wave*(TM/4) + i*16][0]);
        }
        #pragma unroll
        for (int i = 0; i < 2; i++) {
            glds16(Bg + (size_t)(i*16) * K + k0,      &Bs0[wave*32 + i*16][0]);
            glds16(Bg + (size_t)(i*16) * K + k0 + 32, &Bs1[wave*32 + i*16][0]);
        }
        __syncthreads();

        bf16x8 af0[MT], af1[MT], bf0[4], bf1[4];
        #pragma unroll
        for (int mt = 0; mt < MT; mt++) {
            af0[mt] = *(const bf16x8*)&As0[wm*(TM/2) + mt*16 + lrow][quad * 8];
            af1[mt] = *(const bf16x8*)&As1[wm*(TM/2) + mt*16 + lrow][quad * 8];
        }
        #pragma unroll
        for (int nt = 0; nt < 4; nt++) {
            bf0[nt] = *(const bf16x8*)&Bs0[wn*64 + nt*16 + lrow][quad * 8];
            bf1[nt] = *(const bf16x8*)&Bs1[wn*64 + nt*16 + lrow][quad * 8];
        }
        #pragma unroll
        for (int mt = 0; mt < MT; mt++)
            #pragma unroll
            for (int nt = 0; nt < 4; nt++) {
                acc[mt][nt] = __builtin_amdgcn_mfma_f32_16x16x32_bf16(
                    bf0[nt], af0[mt], acc[mt][nt], 0, 0, 0);
                acc[mt][nt] = __builtin_amdgcn_mfma_f32_16x16x32_bf16(
                    bf1[nt], af1[mt], acc[mt][nt], 0, 0, 0);
            }
    }

    int crow0 = m0 + wm * (TM/2);
    int ccol0 = n0 + wn * 64;
    #pragma unroll
    for (int mt = 0; mt < MT; mt++) {
        int row = crow0 + mt * 16 + lrow;
        #pragma unroll
        for (int nt = 0; nt < 4; nt++) {
            int col = ccol0 + nt * 16 + quad * 4;
            size_t off = (size_t)row * ldc + col;
            float4 bv = make_float4(0.f, 0.f, 0.f, 0.f);
            if (bias) bv = *(const float4*)(bias + col);
            float4 rs = make_float4(0.f, 0.f, 0.f, 0.f);
            if (resid) rs = *(const float4*)(resid + off);
            floatx4 a = acc[mt][nt];
            if (Cf) {
                float4 v;
                v.x = a[0] + bv.x + rs.x; v.y = a[1] + bv.y + rs.y;
                v.z = a[2] + bv.z + rs.z; v.w = a[3] + bv.w + rs.w;
                *(float4*)(Cf + off) = v;
            } else {
                bf16x4 v;
                v[0] = (bf16_t)(a[0] + bv.x + rs.x);
                v[1] = (bf16_t)(a[1] + bv.y + rs.y);
                v[2] = (bf16_t)(a[2] + bv.z + rs.z);
                v[3] = (bf16_t)(a[3] + bv.w + rs.w);
                *(bf16x4*)(Cb + off) = v;
            }
        }
    }
}

// ------- merged QKV projection: grid (18, 32) ----------------
// bx < 12: output qk (4096 x 1536, C^T epilogue).  bx >= 12: V with swapped
// MFMA order -> direct-transposed write vt[bh][d][t]. Same R6 loop body.
__global__ __launch_bounds__(256) void gemm_qkv(
    const bf16_t* __restrict__ A, const bf16_t* __restrict__ QKVW,
    bf16_t* __restrict__ qkout, bf16_t* __restrict__ vtout)
{
    const int K = 768;
    __shared__ bf16_t As0[128][32], As1[128][32];
    __shared__ bf16_t Bs0[128][32], Bs1[128][32];
    int tid = threadIdx.x;
    int wave = tid >> 6, lane = tid & 63;
    int lrow = lane & 15, quad = lane >> 4;
    int wm = wave >> 1, wn = wave & 1;

    int bx = blockIdx.x;
    bool isV = (bx >= 12);
    int m0 = blockIdx.y * 128;
    int brow0 = isV ? 1536 + (bx - 12) * 128 : bx * 128;

    int srow = lane >> 2, scol = (lane & 3) * 8;
    const bf16_t* Ag = A    + ((size_t)m0 + wave * 32 + srow) * K + scol;
    const bf16_t* Bg = QKVW + ((size_t)brow0 + wave * 32 + srow) * K + scol;

    floatx4 acc[4][4];
    #pragma unroll
    for (int mt = 0; mt < 4; mt++)
        #pragma unroll
        for (int nt = 0; nt < 4; nt++)
            #pragma unroll
            for (int r = 0; r < 4; r++) acc[mt][nt][r] = 0.f;

    for (int k0 = 0; k0 < K; k0 += 64) {
        __syncthreads();
        #pragma unroll
        for (int i = 0; i < 2; i++) {
            glds16(Ag + (size_t)(i*16) * K + k0,      &As0[wave*32 + i*16][0]);
            glds16(Ag + (size_t)(i*16) * K + k0 + 32, &As1[wave*32 + i*16][0]);
            glds16(Bg + (size_t)(i*16) * K + k0,      &Bs0[wave*32 + i*16][0]);
            glds16(Bg + (size_t)(i*16) * K + k0 + 32, &Bs1[wave*32 + i*16][0]);
        }
        __syncthreads();

        bf16x8 af0[4], af1[4], bf0[4], bf1[4];
        #pragma unroll
        for (int mt = 0; mt < 4; mt++) {
            af0[mt] = *(const bf16x8*)&As0[wm*64 + mt*16 + lrow][quad * 8];
            af1[mt] = *(const bf16x8*)&As1[wm*64 + mt*16 + lrow][quad * 8];
        }
        #pragma unroll
        for (int nt = 0; nt < 4; nt++) {
            bf0[nt] = *(const bf16x8*)&Bs0[wn*64 + nt*16 + lrow][quad * 8];
            bf1[nt] = *(const bf16x8*)&Bs1[wn*64 + nt*16 + lrow][quad * 8];
        }
        if (!isV) {
            #pragma unroll
            for (int mt = 0; mt < 4; mt++)
                #pragma unroll
                for (int nt = 0; nt < 4; nt++) {
                    acc[mt][nt] = __builtin_amdgcn_mfma_f32_16x16x32_bf16(
                        bf0[nt], af0[mt], acc[mt][nt], 0, 0, 0);
                    acc[mt][nt] = __builtin_amdgcn_mfma_f32_16x16x32_bf16(
                        bf1[nt], af1[mt], acc[mt][nt], 0, 0, 0);
                }
        } else {
            #pragma unroll
            for (int mt = 0; mt < 4; mt++)
                #pragma unroll
                for (int nt = 0; nt < 4; nt++) {
                    acc[mt][nt] = __builtin_amdgcn_mfma_f32_16x16x32_bf16(
                        af0[mt], bf0[nt], acc[mt][nt], 0, 0, 0);
                    acc[mt][nt] = __builtin_amdgcn_mfma_f32_16x16x32_bf16(
                        af1[mt], bf1[nt], acc[mt][nt], 0, 0, 0);
                }
        }
    }

    if (!isV) {
        // C^T epilogue: row = m0+wm*64+mt*16+lrow, col = brow0+wn*64+nt*16+quad*4
        int crow0 = m0 + wm * 64;
        int ccol0 = brow0 + wn * 64;
        #pragma unroll
        for (int mt = 0; mt < 4; mt++) {
            int row = crow0 + mt * 16 + lrow;
            #pragma unroll
            for (int nt = 0; nt < 4; nt++) {
                int col = ccol0 + nt * 16 + quad * 4;
                bf16x4 v;
                #pragma unroll
                for (int r = 0; r < 4; r++) v[r] = (bf16_t)acc[mt][nt][r];
                *(bf16x4*)(qkout + (size_t)row * 1536 + col) = v;
            }
        }
    } else {
        // vt epilogue: d = (brow0-1536)+wn*64+nt*16+lrow, t = m0+wm*64+mt*16+quad*4
        #pragma unroll
        for (int nt = 0; nt < 4; nt++) {
            int d = (brow0 - 1536) + wn * 64 + nt * 16 + lrow;
            int h = d >> 6, dl = d & 63;
            #pragma unroll
            for (int mt = 0; mt < 4; mt++) {
                int mg = m0 + wm * 64 + mt * 16 + quad * 4;
                int b = mg >> 11, tl = mg & 2047;
                bf16x4 v;
                #pragma unroll
                for (int r = 0; r < 4; r++) v[r] = (bf16_t)acc[mt][nt][r];
                *(bf16x4*)(vtout + (((size_t)(b * NH + h) * 64 + dl) * TDIM + tl)) = v;
            }
        }
    }
}

// ------- fused FFN1: sw = (h2@W1a + b1a) * silu(h2@W1g + b1g) ----------------
__global__ __launch_bounds__(256) void gemm_ffn1(
    const bf16_t* __restrict__ A, const bf16_t* __restrict__ W1t,
    const float* __restrict__ b1, bf16_t* __restrict__ sw)
{
    const int K = 768;
    __shared__ bf16_t As0[64][32], As1[64][32];
    __shared__ bf16_t Ba0[128][32], Ba1[128][32];
    __shared__ bf16_t Bg0[128][32], Bg1[128][32];
    int tid = threadIdx.x;
    int wave = tid >> 6, lane = tid & 63;
    int lrow = lane & 15, quad = lane >> 4;
    int wm = wave >> 1, wn = wave & 1;

    int m0 = blockIdx.y * 64;
    int n0 = blockIdx.x * 128;

    int srow = lane >> 2, scol = (lane & 3) * 8;
    const bf16_t* Agp = A   + ((size_t)m0 + wave * 16 + srow) * K + scol;
    const bf16_t* Bap = W1t + ((size_t)n0 + wave * 32 + srow) * K + scol;
    const bf16_t* Bgp = W1t + ((size_t)(1536 + n0) + wave * 32 + srow) * K + scol;

    floatx4 acc_a[2][4], acc_g[2][4];
    #pragma unroll
    for (int mt = 0; mt < 2; mt++)
        #pragma unroll
        for (int nt = 0; nt < 4; nt++)
            #pragma unroll
            for (int r = 0; r < 4; r++) { acc_a[mt][nt][r] = 0.f; acc_g[mt][nt][r] = 0.f; }

    for (int k0 = 0; k0 < K; k0 += 64) {
        __syncthreads();
        glds16(Agp + k0,      &As0[wave*16][0]);
        glds16(Agp + k0 + 32, &As1[wave*16][0]);
        #pragma unroll
        for (int i = 0; i < 2; i++) {
            glds16(Bap + (size_t)(i*16) * K + k0,      &Ba0[wave*32 + i*16][0]);
            glds16(Bap + (size_t)(i*16) * K + k0 + 32, &Ba1[wave*32 + i*16][0]);
            glds16(Bgp + (size_t)(i*16) * K + k0,      &Bg0[wave*32 + i*16][0]);
            glds16(Bgp + (size_t)(i*16) * K + k0 + 32, &Bg1[wave*32 + i*16][0]);
        }
        __syncthreads();

        bf16x8 af0[2], af1[2], ba0[4], ba1[4], bg0[4], bg1[4];
        #pragma unroll
        for (int mt = 0; mt < 2; mt++) {
            af0[mt] = *(const bf16x8*)&As0[wm*32 + mt*16 + lrow][quad * 8];
            af1[mt] = *(const bf16x8*)&As1[wm*32 + mt*16 + lrow][quad * 8];
        }
        #pragma unroll
        for (int nt = 0; nt < 4; nt++) {
            ba0[nt] = *(const bf16x8*)&Ba0[wn*64 + nt*16 + lrow][quad * 8];
            ba1[nt] = *(const bf16x8*)&Ba1[wn*64 + nt*16 + lrow][quad * 8];
            bg0[nt] = *(const bf16x8*)&Bg0[wn*64 + nt*16 + lrow][quad * 8];
            bg1[nt] = *(const bf16x8*)&Bg1[wn*64 + nt*16 + lrow][quad * 8];
        }
        #pragma unroll
        for (int mt = 0; mt < 2; mt++)
            #pragma unroll
            for (int nt = 0; nt < 4; nt++) {
                acc_a[mt][nt] = __builtin_amdgcn_mfma_f32_16x16x32_bf16(
                    ba0[nt], af0[mt], acc_a[mt][nt], 0, 0, 0);
                acc_a[mt][nt] = __builtin_amdgcn_mfma_f32_16x16x32_bf16(
                    ba1[nt], af1[mt], acc_a[mt][nt], 0, 0, 0);
                acc_g[mt][nt] = __builtin_amdgcn_mfma_f32_16x16x32_bf16(
                    bg0[nt], af0[mt], acc_g[mt][nt], 0, 0, 0);
                acc_g[mt][nt] = __builtin_amdgcn_mfma_f32_16x16x32_bf16(
                    bg1[nt], af1[mt], acc_g[mt][nt], 0, 0, 0);
            }
    }

    #pragma unroll
    for (int mt = 0; mt < 2; mt++) {
        int row = m0 + wm * 32 + mt * 16 + lrow;
        #pragma unroll
        for (int nt = 0; nt < 4; nt++) {
            int col = n0 + wn * 64 + nt * 16 + quad * 4;
            float4 bva = *(const float4*)(b1 + col);
            float4 bvg = *(const float4*)(b1 + 1536 + col);
            float av[4] = { acc_a[mt][nt][0] + bva.x, acc_a[mt][nt][1] + bva.y,
                            acc_a[mt][nt][2] + bva.z, acc_a[mt][nt][3] + bva.w };
            float gv[4] = { acc_g[mt][nt][0] + bvg.x, acc_g[mt][nt][1] + bvg.y,
                            acc_g[mt][nt][2] + bvg.z, acc_g[mt][nt][3] + bvg.w };
            bf16x4 v;
            #pragma unroll
            for (int r = 0; r < 4; r++)
                v[r] = (bf16_t)(av[r] * (gv[r] / (1.0f + __expf(-gv[r]))));
            *(bf16x4*)(sw + (size_t)row * 1536 + col) = v;
        }
    }
}

// ---------------- MFMA flash attention, S^T form, 128-row Q-tiles ------------
// Each wave owns 32 q rows (2 subtiles of 16). Ks/Vt fragment reads (block-
// uniform A-operands) are amortized over both subtiles -> LDS traffic per unit
// work ~0.69x vs 64-row tiles. Grid 384; rank map pairs heavy+light blocks on
// the same CU: CU c<128 gets ranks {c, 383-c} (sum = 34 K-iters exactly),
// c>=128 gets mid ranks (<=22 iters).
__global__ __launch_bounds__(256) void attn_mfma(
    const bf16_t* __restrict__ qk, const bf16_t* __restrict__ vt,
    bf16_t* __restrict__ o)
{
    const int QS = 1536;
    int bid = blockIdx.x;
    int rank = (bid < 256) ? bid : 639 - bid;
    int qt = 15 - rank / 24;
    int bh = rank % 24;
    int b = bh / NH, h = bh - b * NH;
    int tid = threadIdx.x;
    int wave = tid >> 6, lane = tid & 63;
    int lrow = lane & 15, quad = lane >> 4;

    __shared__ bf16_t Ks[64][72];      // K tile: row = kcol, col = dim
    __shared__ bf16_t Vt[64][72];      // V^T: row = dim, col = kcol
    __shared__ bf16_t Ps[4][32][72];   // per-wave P (row = q_local, col = kc)

    size_t rbase = (size_t)b * TDIM;
    int q0 = qt * 128, qrow_w = q0 + wave * 32;

    bf16x8 qf[2][2];                   // [kf][nq]
    #pragma unroll
    for (int nq = 0; nq < 2; nq++) {
        const bf16_t* qp = qk + (rbase + qrow_w + nq * 16 + lrow) * QS + h * 64;
        qf[0][nq] = *(const bf16x8*)(qp + quad * 8);
        qf[1][nq] = *(const bf16x8*)(qp + 32 + quad * 8);
    }

    floatx4 o_acc[4][2];   // O^T: [mt][nq]; dim = mt*16+quad*4+r, q col = lrow
    #pragma unroll
    for (int mt = 0; mt < 4; mt++)
        #pragma unroll
        for (int nq = 0; nq < 2; nq++)
            #pragma unroll
            for (int r = 0; r < 4; r++) o_acc[mt][nq][r] = 0.f;
    float m_r[2] = {-INFINITY, -INFINITY};
    float l_r[2] = {0.f, 0.f};

    int srow = tid >> 2;            // 0..63
    int scol = (tid & 3) * 16;      // 0,16,32,48

    int niter = 2 * qt + 2;
    for (int s = 0; s < niter; s++) {
        __syncthreads();
        {
            const bf16_t* kp = qk + (rbase + s * 64 + srow) * QS + 768 + h * 64 + scol;
            *(bf16x8*)&Ks[srow][scol]     = *(const bf16x8*)kp;
            *(bf16x8*)&Ks[srow][scol + 8] = *(const bf16x8*)(kp + 8);
            const bf16_t* vp = vt + ((size_t)bh * 64 + srow) * TDIM + s * 64 + scol;
            *(bf16x8*)&Vt[srow][scol]     = *(const bf16x8*)vp;
            *(bf16x8*)&Vt[srow][scol + 8] = *(const bf16x8*)(vp + 8);
        }
        __syncthreads();

        #pragma unroll
        for (int nq = 0; nq < 2; nq++) {
            // S^T = K Q^T : row = kc (nt*16+quad*4+r), col = q (lrow)
            floatx4 sfrag[4];
            #pragma unroll
            for (int nt = 0; nt < 4; nt++) {
                floatx4 a;
                #pragma unroll
                for (int r = 0; r < 4; r++) a[r] = 0.f;
                #pragma unroll
                for (int kf = 0; kf < 2; kf++) {
                    bf16x8 afr = *(const bf16x8*)&Ks[nt * 16 + lrow][kf * 32 + quad * 8];
                    a = __builtin_amdgcn_mfma_f32_16x16x32_bf16(afr, qf[kf][nq], a, 0, 0, 0);
                }
                sfrag[nt] = a;
            }

            int qbase = qrow_w + nq * 16;
            if (s * 64 + 63 > qbase) {          // partially masked tile
                int qg = qbase + lrow;
                #pragma unroll
                for (int nt = 0; nt < 4; nt++)
                    #pragma unroll
                    for (int r = 0; r < 4; r++) {
                        int kc = s * 64 + nt * 16 + quad * 4 + r;
                        sfrag[nt][r] = (kc > qg) ? -INFINITY : sfrag[nt][r] * SCALE;
                    }
            } else {
                #pragma unroll
                for (int nt = 0; nt < 4; nt++)
                    #pragma unroll
                    for (int r = 0; r < 4; r++) sfrag[nt][r] *= SCALE;
            }

            // online softmax over kc: reg-max + 2 shfls
            float mx = sfrag[0][0];
            #pragma unroll
            for (int nt = 0; nt < 4; nt++)
                #pragma unroll
                for (int r = 0; r < 4; r++) mx = fmaxf(mx, sfrag[nt][r]);
            mx = fmaxf(mx, __shfl_xor(mx, 16, 64));
            mx = fmaxf(mx, __shfl_xor(mx, 32, 64));
            float mn = fmaxf(m_r[nq], mx);
            float alpha = __expf(m_r[nq] - mn);
            m_r[nq] = mn;

            float ls = 0.f;
            #pragma unroll
            for (int nt = 0; nt < 4; nt++) {
                bf16x4 pv;
                #pragma unroll
                for (int r = 0; r < 4; r++) {
                    float p2 = __expf(sfrag[nt][r] - mn);
                    ls += p2;
                    pv[r] = (bf16_t)p2;
                }
                *(bf16x4*)&Ps[wave][nq * 16 + lrow][nt * 16 + quad * 4] = pv;
            }
            ls += __shfl_xor(ls, 16, 64);
            ls += __shfl_xor(ls, 32, 64);
            l_r[nq] = l_r[nq] * alpha + ls;
            #pragma unroll
            for (int mt = 0; mt < 4; mt++)
                #pragma unroll
                for (int r = 0; r < 4; r++) o_acc[mt][nq][r] *= alpha;
        }

        // O^T += V^T P^T : Vt frags shared across both q-subtiles
        #pragma unroll
        for (int kf = 0; kf < 2; kf++) {
            bf16x8 pfr[2];
            #pragma unroll
            for (int nq = 0; nq < 2; nq++)
                pfr[nq] = *(const bf16x8*)&Ps[wave][nq * 16 + lrow][kf * 32 + quad * 8];
            #pragma unroll
            for (int mt = 0; mt < 4; mt++) {
                bf16x8 vfr = *(const bf16x8*)&Vt[mt * 16 + lrow][kf * 32 + quad * 8];
                #pragma unroll
                for (int nq = 0; nq < 2; nq++)
                    o_acc[mt][nq] = __builtin_amdgcn_mfma_f32_16x16x32_bf16(
                        vfr, pfr[nq], o_acc[mt][nq], 0, 0, 0);
            }
        }
    }

    #pragma unroll
    for (int nq = 0; nq < 2; nq++) {
        float inv = 1.0f / l_r[nq];
        size_t rb = (rbase + qrow_w + nq * 16 + lrow) * DDIM + h * 64;
        #pragma unroll
        for (int mt = 0; mt < 4; mt++) {
            bf16x4 ov;
            #pragma unroll
            for (int r = 0; r < 4; r++) ov[r] = (bf16_t)(o_acc[mt][nq][r] * inv);
            *(bf16x4*)(o + rb + mt * 16 + quad * 4) = ov;
        }
    }
}

extern "C" void kernel_launch(void* const* d_in, const int* in_sizes, int n_in,
                              void* d_out, int out_size, void* d_ws, size_t ws_size,
                              hipStream_t stream) {
    const float* x  = (const float*)d_in[0];
    const float* Wq = (const float*)d_in[1];
    const float* Wk = (const float*)d_in[2];
    const float* Wv = (const float*)d_in[3];
    const float* Wo = (const float*)d_in[4];
    const float* bo = (const float*)d_in[5];
    const float* W1 = (const float*)d_in[6];
    const float* b1 = (const float*)d_in[7];
    const float* W2 = (const float*)d_in[8];
    const float* b2 = (const float*)d_in[9];
    const float* g1 = (const float*)d_in[10];
    const float* g2 = (const float*)d_in[11];
    float* out = (float*)d_out;
    char* ws = (char*)d_ws;

    bf16_t* qkvw_bt = (bf16_t*)(ws);                    // 2304x768  = 3,538,944 B
    bf16_t* wo_bt   = (bf16_t*)(ws + 3538944);          // 768x768   = 1,179,648
    bf16_t* w1_bt   = (bf16_t*)(ws + 4718592);          // 3072x768  = 4,718,592
    bf16_t* w2_bt   = (bf16_t*)(ws + 9437184);          // 768x1536  = 2,359,296
    bf16_t* h_bf    = (bf16_t*)(ws + 11796480);         // 4096x768  = 6,291,456
    bf16_t* qk      = (bf16_t*)(ws + 18087936);         // 4096x1536 = 12,582,912
    bf16_t* attn_bf = (bf16_t*)(ws + 30670848);         // 4096x768  = 6,291,456
    bf16_t* sw_bf   = (bf16_t*)(ws + 36962304);         // 4096x1536 = 12,582,912
    bf16_t* vt      = (bf16_t*)(ws + 49545216);         // 24x64x2048= 6,291,456
    // total 55,836,672 B

    pack_all<<<1440, 256, 0, stream>>>(Wq, Wk, Wv, Wo, W1, W2,
                                       qkvw_bt, wo_bt, w1_bt, w2_bt);

    rmsnorm_bf<<<NROWS, 256, 0, stream>>>(x, g1, h_bf);

    // qk + vt in one launch (bx<12 -> qk, bx>=12 -> transposed V)
    gemm_qkv<<<dim3(18, 32), 256, 0, stream>>>(h_bf, qkvw_bt, qk, vt);

    attn_mfma<<<384, 256, 0, stream>>>(qk, vt, attn_bf);

    // out = x + attn @ Wo + bo  (fp32)
    gemm_bf16<64><<<dim3(6, 64), 256, 0, stream>>>(
        attn_bf, wo_bt, 768, out, nullptr, 768, bo, x);

    rmsnorm_bf<<<NROWS, 256, 0, stream>>>(out, g2, h_bf);

    // sw = (h2@W1a + b1a) * silu(h2@W1g + b1g)  — fused FFN1 + SwiGLU
    gemm_ffn1<<<dim3(12, 64), 256, 0, stream>>>(h_bf, w1_bt, b1, sw_bf);

    // out = out + sw @ W2 + b2  (fp32)
    gemm_bf16<64><<<dim3(6, 64), 256, 0, stream>>>(
        sw_bf, w2_bt, 1536, out, nullptr, 768, b2, out);
}

// Round 11
// 267.319 us; speedup vs baseline: 1.0859x; 1.0859x over previous
//
#include <hip/hip_runtime.h>
#include <math.h>

// Problem constants: B=2, T=2048, D=768, H=12, HS=64, FF=3072, HALF=1536
#define TDIM 2048
#define DDIM 768
#define NH   12
#define NROWS 4096            // B*T
#define EPSV 1e-8f
#define SCALE 0.03608439182435161f   // 768^-0.5  (ref scales by D, not HS)

typedef __bf16 bf16_t;
typedef bf16_t bf16x8 __attribute__((ext_vector_type(8)));
typedef bf16_t bf16x4 __attribute__((ext_vector_type(4)));
typedef float  floatx4 __attribute__((ext_vector_type(4)));

// async global->LDS, 16B per lane; LDS dest = wave-uniform base + lane*16
__device__ __forceinline__ void glds16(const bf16_t* g, bf16_t* l) {
    __builtin_amdgcn_global_load_lds(
        (const __attribute__((address_space(1))) void*)g,
        (__attribute__((address_space(3))) void*)l, 16, 0, 0);
}

// ------------- unified weight repack: 64x64 fp32->bf16 tile transpose --------
// 1440 blocks: [0,144) Wo, [144,720) W1, [720,1008) W2, [1008,1440) QKV pack.
__global__ __launch_bounds__(256) void pack_all(
    const float* __restrict__ Wq, const float* __restrict__ Wk,
    const float* __restrict__ Wv, const float* __restrict__ Wo,
    const float* __restrict__ W1, const float* __restrict__ W2,
    bf16_t* __restrict__ qkvw, bf16_t* __restrict__ wo,
    bf16_t* __restrict__ w1, bf16_t* __restrict__ w2)
{
    int bid = blockIdx.x;
    const float* src; bf16_t* dst;
    int srcld, dstld, k0, n0;
    if (bid < 144) {                       // Wo: K=768, N=768 (12x12)
        int kx = bid % 12, nx = bid / 12;
        src = Wo; dst = wo; srcld = 768; dstld = 768; k0 = kx * 64; n0 = nx * 64;
    } else if (bid < 720) {                // W1: K=768, N=3072 (12x48)
        int t = bid - 144; int kx = t % 12, nx = t / 12;
        src = W1; dst = w1; srcld = 3072; dstld = 768; k0 = kx * 64; n0 = nx * 64;
    } else if (bid < 1008) {               // W2: K=1536, N=768 (24x12)
        int t = bid - 720; int kx = t % 24, nx = t / 24;
        src = W2; dst = w2; srcld = 768; dstld = 1536; k0 = kx * 64; n0 = nx * 64;
    } else {                               // QKV: 36 mats (768x64), 12 k-tiles
        int t = bid - 1008; int kx = t % 12, y = t / 12;
        int sel = y / 12, h = y - sel * 12;
        src = ((sel == 0) ? Wq : (sel == 1) ? Wk : Wv) + (size_t)h * 768 * 64;
        dst = qkvw + (size_t)(sel * 768 + h * 64) * 768;
        srcld = 64; dstld = 768; k0 = kx * 64; n0 = 0;
    }
    __shared__ float Ts[64][65];
    int tid = threadIdx.x;
    int r = tid >> 2, c = (tid & 3) * 16;
    const float* s = src + (size_t)(k0 + r) * srcld + n0 + c;
    #pragma unroll
    for (int i = 0; i < 4; i++) {
        float4 t = *(const float4*)(s + i * 4);
        Ts[r][c + i*4 + 0] = t.x; Ts[r][c + i*4 + 1] = t.y;
        Ts[r][c + i*4 + 2] = t.z; Ts[r][c + i*4 + 3] = t.w;
    }
    __syncthreads();
    int n = tid >> 2, kk = (tid & 3) * 16;
    bf16x8 o0, o1;
    #pragma unroll
    for (int i = 0; i < 8; i++) {
        o0[i] = (bf16_t)Ts[kk + i][n];
        o1[i] = (bf16_t)Ts[kk + 8 + i][n];
    }
    bf16_t* d = dst + (size_t)(n0 + n) * dstld + k0 + kk;
    *(bf16x8*)d = o0;
    *(bf16x8*)(d + 8) = o1;
}

// ---------------- RMSNorm -> bf16 ----------------
__global__ __launch_bounds__(256) void rmsnorm_bf(
    const float* __restrict__ x, const float* __restrict__ g,
    bf16_t* __restrict__ out)
{
    int row = blockIdx.x;
    int tid = threadIdx.x;
    const float* xr = x + (size_t)row * DDIM;
    float v0 = xr[tid], v1 = xr[tid + 256], v2 = xr[tid + 512];
    float s = v0*v0 + v1*v1 + v2*v2;
    #pragma unroll
    for (int off = 32; off > 0; off >>= 1)
        s += __shfl_down(s, off, 64);
    __shared__ float red[4];
    __shared__ float tot;
    if ((tid & 63) == 0) red[tid >> 6] = s;
    __syncthreads();
    if (tid == 0) tot = red[0] + red[1] + red[2] + red[3];
    __syncthreads();
    float rms = sqrtf(tot * (1.0f / DDIM));
    float inv = 1.0f / (rms + EPSV);
    bf16_t* orow = out + (size_t)row * DDIM;
    orow[tid]       = (bf16_t)(g[tid]       * v0 * inv);
    orow[tid + 256] = (bf16_t)(g[tid + 256] * v1 * inv);
    orow[tid + 512] = (bf16_t)(g[tid + 512] * v2 * inv);
}

// ---------------- bf16 MFMA GEMM, BK=64 twin-buffer, C^T epilogue ------------
// C[M x N] = A[M x K] * BT[N x K]^T. Tile TM x 128, 4 waves 2x2.
// MFMA computed as D = BT_frag * A_frag -> lane holds 4 consecutive C-cols
// of one C-row => vectorized float4 / bf16x4 stores.
template<int TM>
__global__ __launch_bounds__(256) void gemm_bf16(
    const bf16_t* __restrict__ A, const bf16_t* __restrict__ BT, int K,
    float* __restrict__ Cf, bf16_t* __restrict__ Cb, int ldc,
    const float* __restrict__ bias, const float* __restrict__ resid)
{
    constexpr int MT = TM / 32;           // m-frags per wave (4 or 2)
    __shared__ bf16_t As0[TM][32], As1[TM][32];      // 64B rows (m97 layout)
    __shared__ bf16_t Bs0[128][32], Bs1[128][32];
    int tid = threadIdx.x;
    int wave = tid >> 6, lane = tid & 63;
    int lrow = lane & 15, quad = lane >> 4;
    int wm = wave >> 1, wn = wave & 1;

    int m0 = blockIdx.y * TM;
    int n0 = blockIdx.x * 128;

    int srow = lane >> 2, scol = (lane & 3) * 8;     // 16 rows x 8 elems per glds
    const bf16_t* Ag = A  + ((size_t)m0 + wave * (TM/4) + srow) * K + scol;
    const bf16_t* Bg = BT + ((size_t)n0 + wave * 32 + srow) * K + scol;

    floatx4 acc[MT][4];
    #pragma unroll
    for (int mt = 0; mt < MT; mt++)
        #pragma unroll
        for (int nt = 0; nt < 4; nt++)
            #pragma unroll
            for (int r = 0; r < 4; r++) acc[mt][nt][r] = 0.f;

    for (int k0 = 0; k0 < K; k0 += 64) {
        __syncthreads();
        #pragma unroll
        for (int i = 0; i < TM/64; i++) {            // 2 (TM=128) or 1 (TM=64)
            glds16(Ag + (size_t)(i*16) * K + k0,      &As0[wave*(TM/4) + i*16][0]);
            glds16(Ag + (size_t)(i*16) * K + k0 + 32, &As1[wave*(TM/4) + i*16][0]);
        }
        #pragma unroll
        for (int i = 0; i < 2; i++) {
            glds16(Bg + (size_t)(i*16) * K + k0,      &Bs0[wave*32 + i*16][0]);
            glds16(Bg + (size_t)(i*16) * K + k0 + 32, &Bs1[wave*32 + i*16][0]);
        }
        __syncthreads();

        bf16x8 af0[MT], af1[MT], bf0[4], bf1[4];
        #pragma unroll
        for (int mt = 0; mt < MT; mt++) {
            af0[mt] = *(const bf16x8*)&As0[wm*(TM/2) + mt*16 + lrow][quad * 8];
            af1[mt] = *(const bf16x8*)&As1[wm*(TM/2) + mt*16 + lrow][quad * 8];
        }
        #pragma unroll
        for (int nt = 0; nt < 4; nt++) {
            bf0[nt] = *(const bf16x8*)&Bs0[wn*64 + nt*16 + lrow][quad * 8];
            bf1[nt] = *(const bf16x8*)&Bs1[wn*64 + nt*16 + lrow][quad * 8];
        }
        #pragma unroll
        for (int mt = 0; mt < MT; mt++)
            #pragma unroll
            for (int nt = 0; nt < 4; nt++) {
                acc[mt][nt] = __builtin_amdgcn_mfma_f32_16x16x32_bf16(
                    bf0[nt], af0[mt], acc[mt][nt], 0, 0, 0);
                acc[mt][nt] = __builtin_amdgcn_mfma_f32_16x16x32_bf16(
                    bf1[nt], af1[mt], acc[mt][nt], 0, 0, 0);
            }
    }

    // epilogue (C^T layout): row = m0+wm*(TM/2)+mt*16+lrow,
    //                        col = n0+wn*64+nt*16+quad*4 .. +4
    int crow0 = m0 + wm * (TM/2);
    int ccol0 = n0 + wn * 64;
    #pragma unroll
    for (int mt = 0; mt < MT; mt++) {
        int row = crow0 + mt * 16 + lrow;
        #pragma unroll
        for (int nt = 0; nt < 4; nt++) {
            int col = ccol0 + nt * 16 + quad * 4;
            size_t off = (size_t)row * ldc + col;
            float4 bv = make_float4(0.f, 0.f, 0.f, 0.f);
            if (bias) bv = *(const float4*)(bias + col);
            float4 rs = make_float4(0.f, 0.f, 0.f, 0.f);
            if (resid) rs = *(const float4*)(resid + off);
            floatx4 a = acc[mt][nt];
            if (Cf) {
                float4 v;
                v.x = a[0] + bv.x + rs.x; v.y = a[1] + bv.y + rs.y;
                v.z = a[2] + bv.z + rs.z; v.w = a[3] + bv.w + rs.w;
                *(float4*)(Cf + off) = v;
            } else {
                bf16x4 v;
                v[0] = (bf16_t)(a[0] + bv.x + rs.x);
                v[1] = (bf16_t)(a[1] + bv.y + rs.y);
                v[2] = (bf16_t)(a[2] + bv.z + rs.z);
                v[3] = (bf16_t)(a[3] + bv.w + rs.w);
                *(bf16x4*)(Cb + off) = v;
            }
        }
    }
}

// ---------------- V transpose: qkv V-part -> vt[bh][dim][t] ----------------
__global__ __launch_bounds__(256) void vt_kernel(
    const bf16_t* __restrict__ qkv, bf16_t* __restrict__ vt)
{
    __shared__ bf16_t Ts[64][72];
    int t0 = blockIdx.x * 64;
    int bh = blockIdx.y;
    int b = bh / NH, h = bh - b * NH;
    int tid = threadIdx.x;
    int r = tid >> 2, c = (tid & 3) * 16;
    const bf16_t* src = qkv + ((size_t)b * TDIM + t0 + r) * 2304 + 1536 + h * 64 + c;
    *(bf16x8*)&Ts[r][c]     = *(const bf16x8*)src;
    *(bf16x8*)&Ts[r][c + 8] = *(const bf16x8*)(src + 8);
    __syncthreads();
    int d = tid >> 2, tt = (tid & 3) * 16;
    bf16x8 o0, o1;
    #pragma unroll
    for (int i = 0; i < 8; i++) {
        o0[i] = Ts[tt + i][d];
        o1[i] = Ts[tt + 8 + i][d];
    }
    bf16_t* dst = vt + ((size_t)bh * 64 + d) * TDIM + t0 + tt;
    *(bf16x8*)dst = o0;
    *(bf16x8*)(dst + 8) = o1;
}

// ---------------- MFMA flash attention, S^T formulation ----------------
// Serpentine cost-balanced mapping (R9-validated): co-resident blocks
// {c, c+256, c+512} get ranks {c, 511-c, 512+c}; cost(rank) ~ 32 - rank/24
// -> per-CU cost in [42.8, 53.4] units (old 3-slot worst was 65).
__global__ __launch_bounds__(256) void attn_mfma(
    const bf16_t* __restrict__ qkv, const bf16_t* __restrict__ vt,
    bf16_t* __restrict__ o)
{
    const int QS = 2304;
    int bid = blockIdx.x;
    int p = bid >> 8, idx = bid & 255;
    int rank = (p == 1) ? (511 - idx) : (p * 256 + idx);  // serpentine deal
    int qt = 31 - rank / 24;            // rank 0 = biggest tile (qt=31)
    int bh = rank % 24;
    int b = bh / NH, h = bh - b * NH;
    int tid = threadIdx.x;
    int wave = tid >> 6, lane = tid & 63;
    int lrow = lane & 15, quad = lane >> 4;

    __shared__ bf16_t Ks[64][72];      // K tile: row = kcol, col = dim
    __shared__ bf16_t Vt[64][72];      // V^T: row = dim, col = kcol
    __shared__ bf16_t Ps[4][16][72];   // per-wave P (row = q, col = kc)

    size_t rbase = (size_t)b * TDIM;
    int q0 = qt * 64, qrow_w = q0 + wave * 16;

    const bf16_t* qp = qkv + (rbase + qrow_w + lrow) * QS + h * 64;
    bf16x8 qf[2];
    qf[0] = *(const bf16x8*)(qp + quad * 8);
    qf[1] = *(const bf16x8*)(qp + 32 + quad * 8);

    floatx4 o_acc[4];   // O^T: (dim = mt*16 + quad*4 + r, q = lrow)
    #pragma unroll
    for (int mt = 0; mt < 4; mt++)
        #pragma unroll
        for (int r = 0; r < 4; r++) o_acc[mt][r] = 0.f;
    float m_r = -INFINITY, l_r = 0.f;

    int srow = tid >> 2;            // 0..63
    int scol = (tid & 3) * 16;      // 0,16,32,48

    for (int s = 0; s <= qt; s++) {
        __syncthreads();
        {
            const bf16_t* kp = qkv + (rbase + s * 64 + srow) * QS + 768 + h * 64 + scol;
            *(bf16x8*)&Ks[srow][scol]     = *(const bf16x8*)kp;
            *(bf16x8*)&Ks[srow][scol + 8] = *(const bf16x8*)(kp + 8);
            const bf16_t* vp = vt + ((size_t)bh * 64 + srow) * TDIM + s * 64 + scol;
            *(bf16x8*)&Vt[srow][scol]     = *(const bf16x8*)vp;
            *(bf16x8*)&Vt[srow][scol + 8] = *(const bf16x8*)(vp + 8);
        }
        __syncthreads();

        // S^T = K Q^T : C row = kc (nt*16 + quad*4 + r), col = q (lrow)
        floatx4 sfrag[4];
        #pragma unroll
        for (int nt = 0; nt < 4; nt++) {
            floatx4 a;
            #pragma unroll
            for (int r = 0; r < 4; r++) a[r] = 0.f;
            #pragma unroll
            for (int kf = 0; kf < 2; kf++) {
                bf16x8 afr = *(const bf16x8*)&Ks[nt * 16 + lrow][kf * 32 + quad * 8];
                a = __builtin_amdgcn_mfma_f32_16x16x32_bf16(afr, qf[kf], a, 0, 0, 0);
            }
            sfrag[nt] = a;
        }

        // scale + causal mask (diagonal tile only); kc > q masked
        if (s == qt) {
            int qg = qrow_w + lrow;
            #pragma unroll
            for (int nt = 0; nt < 4; nt++)
                #pragma unroll
                for (int r = 0; r < 4; r++) {
                    int kc = s * 64 + nt * 16 + quad * 4 + r;
                    sfrag[nt][r] = (kc > qg) ? -INFINITY : sfrag[nt][r] * SCALE;
                }
        } else {
            #pragma unroll
            for (int nt = 0; nt < 4; nt++)
                #pragma unroll
                for (int r = 0; r < 4; r++) sfrag[nt][r] *= SCALE;
        }

        // online softmax over kc: reg-max + 2 shfls
        float mx = sfrag[0][0];
        #pragma unroll
        for (int nt = 0; nt < 4; nt++)
            #pragma unroll
            for (int r = 0; r < 4; r++) mx = fmaxf(mx, sfrag[nt][r]);
        mx = fmaxf(mx, __shfl_xor(mx, 16, 64));
        mx = fmaxf(mx, __shfl_xor(mx, 32, 64));
        float mn = fmaxf(m_r, mx);
        float alpha = __expf(m_r - mn);
        m_r = mn;

        float ls = 0.f;
        #pragma unroll
        for (int nt = 0; nt < 4; nt++) {
            bf16x4 pv;
            #pragma unroll
            for (int r = 0; r < 4; r++) {
                float p2 = __expf(sfrag[nt][r] - mn);
                ls += p2;
                pv[r] = (bf16_t)p2;
            }
            *(bf16x4*)&Ps[wave][lrow][nt * 16 + quad * 4] = pv;
        }
        ls += __shfl_xor(ls, 16, 64);
        ls += __shfl_xor(ls, 32, 64);
        l_r = l_r * alpha + ls;
        #pragma unroll
        for (int mt = 0; mt < 4; mt++)
            #pragma unroll
            for (int r = 0; r < 4; r++) o_acc[mt][r] *= alpha;

        // O^T += V^T P^T (wave-private Ps: no barrier needed)
        #pragma unroll
        for (int kf = 0; kf < 2; kf++) {
            bf16x8 pfr = *(const bf16x8*)&Ps[wave][lrow][kf * 32 + quad * 8];
            #pragma unroll
            for (int mt = 0; mt < 4; mt++) {
                bf16x8 vfr = *(const bf16x8*)&Vt[mt * 16 + lrow][kf * 32 + quad * 8];
                o_acc[mt] = __builtin_amdgcn_mfma_f32_16x16x32_bf16(vfr, pfr, o_acc[mt], 0, 0, 0);
            }
        }
    }

    float inv = 1.0f / l_r;
    size_t rb = (rbase + qrow_w + lrow) * DDIM + h * 64;
    #pragma unroll
    for (int mt = 0; mt < 4; mt++) {
        bf16x4 ov;
        #pragma unroll
        for (int r = 0; r < 4; r++) ov[r] = (bf16_t)(o_acc[mt][r] * inv);
        *(bf16x4*)(o + rb + mt * 16 + quad * 4) = ov;
    }
}

// ---------------- SwiGLU ----------------
__global__ __launch_bounds__(192) void swiglu_bf(
    const bf16_t* __restrict__ u, bf16_t* __restrict__ sw)
{
    int row = blockIdx.x;
    int j0 = threadIdx.x * 8;
    bf16x8 a = *(const bf16x8*)(u + (size_t)row * 3072 + j0);
    bf16x8 g = *(const bf16x8*)(u + (size_t)row * 3072 + 1536 + j0);
    bf16x8 r;
    #pragma unroll
    for (int i = 0; i < 8; i++) {
        float gv = (float)g[i];
        r[i] = (bf16_t)((float)a[i] * (gv / (1.0f + __expf(-gv))));
    }
    *(bf16x8*)(sw + (size_t)row * 1536 + j0) = r;
}

extern "C" void kernel_launch(void* const* d_in, const int* in_sizes, int n_in,
                              void* d_out, int out_size, void* d_ws, size_t ws_size,
                              hipStream_t stream) {
    const float* x  = (const float*)d_in[0];
    const float* Wq = (const float*)d_in[1];
    const float* Wk = (const float*)d_in[2];
    const float* Wv = (const float*)d_in[3];
    const float* Wo = (const float*)d_in[4];
    const float* bo = (const float*)d_in[5];
    const float* W1 = (const float*)d_in[6];
    const float* b1 = (const float*)d_in[7];
    const float* W2 = (const float*)d_in[8];
    const float* b2 = (const float*)d_in[9];
    const float* g1 = (const float*)d_in[10];
    const float* g2 = (const float*)d_in[11];
    float* out = (float*)d_out;
    char* ws = (char*)d_ws;

    bf16_t* qkvw_bt = (bf16_t*)(ws);                    // 2304x768
    bf16_t* wo_bt   = (bf16_t*)(ws + 3538944);          // 768x768
    bf16_t* w1_bt   = (bf16_t*)(ws + 4718592);          // 3072x768
    bf16_t* w2_bt   = (bf16_t*)(ws + 9437184);          // 768x1536
    bf16_t* h_bf    = (bf16_t*)(ws + 11796480);         // 4096x768
    bf16_t* qkv     = (bf16_t*)(ws + 18087936);         // 4096x2304
    bf16_t* attn_bf = (bf16_t*)(ws + 36962304);         // 4096x768
    bf16_t* u_bf    = (bf16_t*)(ws + 43253760);         // 4096x3072
    bf16_t* sw_bf   = (bf16_t*)(ws + 68419584);         // 4096x1536
    bf16_t* vt      = (bf16_t*)(ws + 81002496);         // 24x64x2048

    pack_all<<<1440, 256, 0, stream>>>(Wq, Wk, Wv, Wo, W1, W2,
                                       qkvw_bt, wo_bt, w1_bt, w2_bt);

    rmsnorm_bf<<<NROWS, 256, 0, stream>>>(x, g1, h_bf);

    // qkv = h @ [Wq|Wk|Wv]  (4096 x 2304 bf16)
    gemm_bf16<128><<<dim3(18, 32), 256, 0, stream>>>(
        h_bf, qkvw_bt, 768, nullptr, qkv, 2304, nullptr, nullptr);

    vt_kernel<<<dim3(32, 24), 256, 0, stream>>>(qkv, vt);

    attn_mfma<<<768, 256, 0, stream>>>(qkv, vt, attn_bf);

    // out = x + attn @ Wo + bo  (fp32), TM=64 -> 384 blocks
    gemm_bf16<64><<<dim3(6, 64), 256, 0, stream>>>(
        attn_bf, wo_bt, 768, out, nullptr, 768, bo, x);

    rmsnorm_bf<<<NROWS, 256, 0, stream>>>(out, g2, h_bf);

    // u = h2 @ W1 + b1  (4096 x 3072 bf16)
    gemm_bf16<128><<<dim3(24, 32), 256, 0, stream>>>(
        h_bf, w1_bt, 768, nullptr, u_bf, 3072, b1, nullptr);

    swiglu_bf<<<NROWS, 192, 0, stream>>>(u_bf, sw_bf);

    // out = out + sw @ W2 + b2  (fp32), TM=64 -> 384 blocks
    gemm_bf16<64><<<dim3(6, 64), 256, 0, stream>>>(
        sw_bf, w2_bt, 1536, out, nullptr, 768, b2, out);
}